// Round 2
// baseline (748.630 us; speedup 1.0000x reference)
//
#include <hip/hip_runtime.h>

// WaveNet forward, suffix-window formulation.
// Constants from the reference:
#define BATCH   16
#define CLASSES 256
#define TLEN    4096
#define RC      32      // RES_CH == DIL_CH
#define SKIPC   256
#define ENDC    256
#define NLAYERS 30
#define OUT_T   32

// h buffers are indexed by global time t in [0,4096) with stride TLEN:
// h[(b*RC + c)*TLEN + t]. Layer i consumes window [A_i, 4095], produces
// [A_{i+1}, 4095], A_i = 4064 - S_i, S_i = sum_{j>=i} d_j, d_j = 2^(j%10).

// ---------------------------------------------------------------- causal conv
// h0[b][c][t] = causal_b[c] + sum_cc causal_w[c][cc] * x[b][cc][t], t in [995,4095]
__global__ __launch_bounds__(256) void causal_kernel(
    const float* __restrict__ x, const float* __restrict__ w,
    const float* __restrict__ bias, float* __restrict__ h0)
{
    const int NT = 97;                 // 97 tiles * 32 = 3104 >= 3101
    int b    = blockIdx.x / NT;
    int tile = blockIdx.x % NT;
    int t0   = 995 + tile * 32;

    __shared__ float xs[CLASSES][32];      // x[b][cc][t0..t0+31]
    __shared__ float wsm[CLASSES][33];     // wsm[cc][c] = w[c][cc]  (pad 33)

    for (int idx = threadIdx.x; idx < CLASSES * 32; idx += 256) {
        int cc = idx >> 5, j = idx & 31;
        int t = t0 + j;
        xs[cc][j] = (t < TLEN) ? x[((size_t)b * CLASSES + cc) * TLEN + t] : 0.0f;
    }
    for (int idx = threadIdx.x; idx < RC * CLASSES; idx += 256) {
        int c = idx >> 8, cc = idx & 255;  // idx = c*256+cc (coalesced read)
        wsm[cc][c] = w[idx];
    }
    __syncthreads();

    int c  = threadIdx.x & 31;
    int jb = threadIdx.x >> 5;             // 0..7, owns times jb*4..jb*4+3
    float acc0 = 0.f, acc1 = 0.f, acc2 = 0.f, acc3 = 0.f;
    for (int cc = 0; cc < CLASSES; ++cc) {
        float wv = wsm[cc][c];
        const float4* xr = (const float4*)&xs[cc][0];
        float4 xv = xr[jb];
        acc0 += wv * xv.x; acc1 += wv * xv.y;
        acc2 += wv * xv.z; acc3 += wv * xv.w;
    }
    float bb = bias[c];
    float accs[4] = {acc0, acc1, acc2, acc3};
    #pragma unroll
    for (int k = 0; k < 4; ++k) {
        int t = t0 + jb * 4 + k;
        if (t < TLEN) h0[((size_t)b * RC + c) * TLEN + t] = accs[k] + bb;
    }
}

// ---------------------------------------------------------------- layer kernel
// For t in [A1, 4095]:
//   pre_f(t) = bf + Wf0*h(t-d) + Wf1*h(t);  pre_g analogous
//   z(t) = tanh(pre_f)*sigmoid(pre_g)
//   hout(t) = hin(t) + br + Wr*z(t)
// Tile: 64 times x 32 channels per block; tile 0 anchored at t=4095.
__global__ __launch_bounds__(256) void layer_kernel(
    const float* __restrict__ hin, float* __restrict__ hout,
    float* __restrict__ zb,
    const float* __restrict__ filt_w, const float* __restrict__ filt_b,
    const float* __restrict__ gate_w, const float* __restrict__ gate_b,
    const float* __restrict__ res_w,  const float* __restrict__ res_b,
    int layer, int d, int A1, int nTiles)
{
    int tile = blockIdx.x % nTiles;
    int b    = blockIdx.x / nTiles;
    int t_lo = 4032 - 64 * tile;           // tile covers [t_lo, t_lo+63]

    __shared__ float hc[RC][68];           // h(t)   (68: float4-aligned pad)
    __shared__ float hp[RC][68];           // h(t-d)  (reused as out staging)
    __shared__ float zt[RC][68];           // z(t)
    __shared__ float wf0[RC][33], wf1[RC][33];
    __shared__ float wg0[RC][33], wg1[RC][33];
    __shared__ float wrs[RC][33];
    __shared__ float bfs[RC], bgs[RC], brs[RC];

    {
        const float* fw = filt_w + (size_t)layer * RC * RC * 2;
        const float* gw = gate_w + (size_t)layer * RC * RC * 2;
        const float* rw = res_w  + (size_t)layer * RC * RC;
        for (int idx = threadIdx.x; idx < RC * RC; idx += 256) {
            int c = idx >> 5, c2 = idx & 31;
            wf0[c][c2] = fw[idx * 2];  wf1[c][c2] = fw[idx * 2 + 1];
            wg0[c][c2] = gw[idx * 2];  wg1[c][c2] = gw[idx * 2 + 1];
            wrs[c][c2] = rw[idx];
        }
        if (threadIdx.x < RC) {
            bfs[threadIdx.x] = filt_b[layer * RC + threadIdx.x];
            bgs[threadIdx.x] = gate_b[layer * RC + threadIdx.x];
            brs[threadIdx.x] = res_b[layer * RC + threadIdx.x];
        }
    }
    for (int idx = threadIdx.x; idx < RC * 64; idx += 256) {
        int c2 = idx >> 6, tx = idx & 63;
        const float* row = hin + ((size_t)b * RC + c2) * TLEN;
        int t = t_lo + tx;                 // always within [0,4096)
        hc[c2][tx] = row[t];
        hp[c2][tx] = row[t - d];
    }
    __syncthreads();

    int c  = threadIdx.x & 31;
    int tl = threadIdx.x >> 5;             // 0..7, owns tx = tl*8 .. tl*8+7
    float fa[8], ga[8];
    float bfv = bfs[c], bgv = bgs[c];
    #pragma unroll
    for (int k = 0; k < 8; ++k) { fa[k] = bfv; ga[k] = bgv; }

    #pragma unroll 4
    for (int c2 = 0; c2 < RC; ++c2) {
        float w0f = wf0[c][c2], w1f = wf1[c][c2];
        float w0g = wg0[c][c2], w1g = wg1[c][c2];
        const float4* hcr = (const float4*)&hc[c2][0];
        const float4* hpr = (const float4*)&hp[c2][0];
        float4 c0 = hcr[tl * 2], c1 = hcr[tl * 2 + 1];
        float4 p0 = hpr[tl * 2], p1 = hpr[tl * 2 + 1];
        float hcv[8] = {c0.x, c0.y, c0.z, c0.w, c1.x, c1.y, c1.z, c1.w};
        float hpv[8] = {p0.x, p0.y, p0.z, p0.w, p1.x, p1.y, p1.z, p1.w};
        #pragma unroll
        for (int k = 0; k < 8; ++k) {
            fa[k] += w0f * hpv[k] + w1f * hcv[k];
            ga[k] += w0g * hpv[k] + w1g * hcv[k];
        }
    }
    #pragma unroll
    for (int k = 0; k < 8; ++k) {
        float e2 = __expf(2.0f * fa[k]);
        float th = 1.0f - 2.0f / (e2 + 1.0f);       // tanh, overflow-safe
        float sg = 1.0f / (1.0f + __expf(-ga[k]));  // sigmoid
        zt[c][tl * 8 + k] = th * sg;
    }
    __syncthreads();

    float ra[8];
    float brv = brs[c];
    #pragma unroll
    for (int k = 0; k < 8; ++k) ra[k] = brv;
    #pragma unroll 4
    for (int c2 = 0; c2 < RC; ++c2) {
        float wv = wrs[c][c2];
        const float4* zr = (const float4*)&zt[c2][0];
        float4 z0 = zr[tl * 2], z1 = zr[tl * 2 + 1];
        float zv[8] = {z0.x, z0.y, z0.z, z0.w, z1.x, z1.y, z1.z, z1.w};
        #pragma unroll
        for (int k = 0; k < 8; ++k) ra[k] += wv * zv[k];
    }
    // out(t) = hin(t) + res;  stage to LDS (reuse hp) for coalesced writeback
    #pragma unroll
    for (int k = 0; k < 8; ++k) {
        int tx = tl * 8 + k;
        hp[c][tx] = hc[c][tx] + ra[k];
    }
    __syncthreads();

    for (int idx = threadIdx.x; idx < RC * 64; idx += 256) {
        int c2 = idx >> 6, tx = idx & 63;
        int t = t_lo + tx;
        if (t >= A1) hout[((size_t)b * RC + c2) * TLEN + t] = hp[c2][tx];
    }
    if (tile == 0) {   // z tail for skip path: t in [4064,4095] -> tx in [32,64)
        for (int idx = threadIdx.x; idx < RC * OUT_T; idx += 256) {
            int c2 = idx >> 5, tt = idx & 31;
            zb[(((size_t)layer * BATCH + b) * RC + c2) * OUT_T + tt] = zt[c2][32 + tt];
        }
    }
}

// ---------------------------------------------------------------- end kernel
// skip[b][sc][tt] = sum_i ( skip_b[i][sc] + sum_c skip_w[i][sc][c]*z_i[b][c][tt] )
// out = end2_w * relu(end1_w * relu(skip) + end1_b) + end2_b, row (b*32+tt)
__global__ __launch_bounds__(256) void end_kernel(
    const float* __restrict__ zb,
    const float* __restrict__ skip_w, const float* __restrict__ skip_b,
    const float* __restrict__ e1w, const float* __restrict__ e1b,
    const float* __restrict__ e2w, const float* __restrict__ e2b,
    float* __restrict__ out)
{
    int b  = blockIdx.x >> 5;
    int tt = blockIdx.x & 31;

    __shared__ float zv[NLAYERS * RC];   // 960
    __shared__ float sv[SKIPC];
    __shared__ float e1[ENDC];

    for (int idx = threadIdx.x; idx < NLAYERS * RC; idx += 256) {
        int i = idx >> 5, c = idx & 31;
        zv[idx] = zb[(((size_t)i * BATCH + b) * RC + c) * OUT_T + tt];
    }
    __syncthreads();

    int sc = threadIdx.x;
    float acc = 0.0f;
    for (int i = 0; i < NLAYERS; ++i) {
        acc += skip_b[i * SKIPC + sc];
        const float* sw = skip_w + ((size_t)i * SKIPC + sc) * RC;
        #pragma unroll 8
        for (int c2 = 0; c2 < RC; ++c2) acc += sw[c2] * zv[i * RC + c2];
    }
    sv[sc] = fmaxf(acc, 0.0f);
    __syncthreads();

    float a1 = e1b[sc];
    const float* w1 = e1w + (size_t)sc * SKIPC;
    #pragma unroll 8
    for (int k = 0; k < SKIPC; ++k) a1 += w1[k] * sv[k];
    e1[sc] = fmaxf(a1, 0.0f);
    __syncthreads();

    float a2 = e2b[sc];
    const float* w2 = e2w + (size_t)sc * ENDC;
    #pragma unroll 8
    for (int k = 0; k < ENDC; ++k) a2 += w2[k] * e1[k];
    out[(size_t)blockIdx.x * CLASSES + sc] = a2;   // row = b*32+tt, col = sc
}

// ---------------------------------------------------------------- launch
extern "C" void kernel_launch(void* const* d_in, const int* in_sizes, int n_in,
                              void* d_out, int out_size, void* d_ws, size_t ws_size,
                              hipStream_t stream)
{
    const float* x        = (const float*)d_in[0];
    const float* causal_w = (const float*)d_in[1];
    const float* causal_b = (const float*)d_in[2];
    const float* filt_w   = (const float*)d_in[3];
    const float* filt_b   = (const float*)d_in[4];
    const float* gate_w   = (const float*)d_in[5];
    const float* gate_b   = (const float*)d_in[6];
    const float* res_w    = (const float*)d_in[7];
    const float* res_b    = (const float*)d_in[8];
    const float* skip_w   = (const float*)d_in[9];
    const float* skip_b   = (const float*)d_in[10];
    const float* e1w      = (const float*)d_in[11];
    const float* e1b      = (const float*)d_in[12];
    const float* e2w      = (const float*)d_in[13];
    const float* e2b      = (const float*)d_in[14];

    const size_t HSZ = (size_t)BATCH * RC * TLEN;  // 2,097,152 floats
    float* hA = (float*)d_ws;
    float* hB = hA + HSZ;
    float* zb = hB + HSZ;                          // NLAYERS*BATCH*RC*OUT_T

    causal_kernel<<<dim3(BATCH * 97), dim3(256), 0, stream>>>(x, causal_w, causal_b, hA);

    float* bufs[2] = {hA, hB};
    int S = 3069;                                  // S_0 = sum of all dilations
    for (int i = 0; i < NLAYERS; ++i) {
        int d = 1 << (i % 10);
        S -= d;                                    // S_{i+1}
        int A1    = 4064 - S;
        int nOut  = 4096 - A1;
        int nTiles = (nOut + 63) / 64;
        const float* hin = bufs[i & 1];
        float*       ho  = bufs[(i & 1) ^ 1];
        layer_kernel<<<dim3(BATCH * nTiles), dim3(256), 0, stream>>>(
            hin, ho, zb, filt_w, filt_b, gate_w, gate_b, res_w, res_b,
            i, d, A1, nTiles);
    }

    end_kernel<<<dim3(BATCH * OUT_T), dim3(256), 0, stream>>>(
        zb, skip_w, skip_b, e1w, e1b, e2w, e2b, (float*)d_out);
}